// Round 6
// baseline (317.168 us; speedup 1.0000x reference)
//
#include <hip/hip_runtime.h>
#include <math.h>

#define DM 1024
#define NH 16
#define DH 64
#define BB 4
#define SS 2048
#define MROWS (BB*SS)

typedef __bf16 bf16;
typedef __bf16 bf16x8 __attribute__((ext_vector_type(8)));
typedef float floatx4 __attribute__((ext_vector_type(4)));

#if __has_builtin(__builtin_amdgcn_exp2f)
#define EXP2F __builtin_amdgcn_exp2f
#else
#define EXP2F exp2f
#endif

#define QSCALE (0.125f * 1.44269504088896f)  // Dh^-0.5 * log2(e)

// async 16B global->LDS; lds dest = wave-uniform base + lane*16 (HW rule)
__device__ __forceinline__ void cp16(void* lds, const void* g) {
  __builtin_amdgcn_global_load_lds(
      (__attribute__((address_space(1))) void*)(void*)g,
      (__attribute__((address_space(3))) void*)lds,
      16, 0, 0);
}

// ---------------------------------------------------------------------------
// x: fp32 -> bf16
// ---------------------------------------------------------------------------
__global__ __launch_bounds__(256) void cvt_x(
    const float* __restrict__ X, bf16* __restrict__ Y) {
  int i = (blockIdx.x * 256 + threadIdx.x) * 8;
  float4 a = *(const float4*)&X[i];
  float4 b = *(const float4*)&X[i + 4];
  bf16x8 o;
  o[0] = (bf16)a.x; o[1] = (bf16)a.y; o[2] = (bf16)a.z; o[3] = (bf16)a.w;
  o[4] = (bf16)b.x; o[5] = (bf16)b.y; o[6] = (bf16)b.z; o[7] = (bf16)b.w;
  *(bf16x8*)&Y[i] = o;
}

// ---------------------------------------------------------------------------
// Weight convert+transpose: T[n][k] = (bf16)W[k][n].
// T0..T2 land contiguously (the fused QKV weight [3072][1024]); T3 = WoT.
// ---------------------------------------------------------------------------
__global__ __launch_bounds__(1024) void wtransc(
    const float* __restrict__ W0, const float* __restrict__ W1,
    const float* __restrict__ W2, const float* __restrict__ W3,
    bf16* __restrict__ T0, bf16* __restrict__ T1,
    bf16* __restrict__ T2, bf16* __restrict__ T3) {
  __shared__ float tile[32][33];
  const float* W; bf16* T;
  int z = blockIdx.z;
  if (z == 0)      { W = W0; T = T0; }
  else if (z == 1) { W = W1; T = T1; }
  else if (z == 2) { W = W2; T = T2; }
  else             { W = W3; T = T3; }
  int tx = threadIdx.x, ty = threadIdx.y;
  tile[ty][tx] = W[(blockIdx.y * 32 + ty) * DM + blockIdx.x * 32 + tx];
  __syncthreads();
  T[(blockIdx.x * 32 + ty) * DM + blockIdx.y * 32 + tx] = (bf16)tile[tx][ty];
}

// ---------------------------------------------------------------------------
// Fused QKV GEMM: [8192,1024] @ WqkvT[3072,1024]^T + bias.  128x128 tile,
// grid (24,64), 4 waves of 64x64, BK=32, global_load_lds double-buffer with
// single barrier per k-step.  Epilogue by output stream:
//   Q: (acc+b)*QSCALE -> qb          K: acc+b -> kb
//   V: acc+b -> LDS tile -> TRANSPOSED store into vt[d][s]  (kills vtrans)
// ---------------------------------------------------------------------------
#define BK 32
#define TST 136  // V-transpose LDS tile stride (272 B = 17*16: b128-aligned)

__global__ __launch_bounds__(256, 3) void gemm_qkv(
    const bf16* __restrict__ A, const bf16* __restrict__ WT,
    const float* __restrict__ bq, const float* __restrict__ bk,
    const float* __restrict__ bv,
    bf16* __restrict__ qb, bf16* __restrict__ kb, bf16* __restrict__ vt) {
  __shared__ __align__(16) char smem[2 * 128 * BK * 2 * 2 > 128 * TST * 2
                                         ? 2 * 128 * BK * 2 * 2
                                         : 128 * TST * 2];
  bf16* As = (bf16*)smem;                    // [2][128*BK]
  bf16* Bs = (bf16*)smem + 2 * 128 * BK;     // [2][128*BK]
  bf16* Ts = (bf16*)smem;                    // [128][TST] (aliases, post-loop)

  int tid = threadIdx.x;
  int lane = tid & 63, w = tid >> 6;
  int wm = (w >> 1) * 64;
  int wn = (w & 1) * 64;
  int m0 = blockIdx.y * 128;
  int n0 = blockIdx.x * 128;      // global over 3072
  int which = n0 >> 10;           // 0=Q 1=K 2=V
  int qd = lane >> 4;
  int l15 = lane & 15;

  floatx4 acc[4][4] = {};

  auto stage = [&](int pb, int k0) {
    for (int i = 0; i < 2; ++i) {
      int ci = (w * 2 + i) * 64;
      int c = ci + lane;
      int r = c >> 2, cc = (c & 3) * 8;
      cp16(&As[pb * 128 * BK + ci * 8], &A[(size_t)(m0 + r) * DM + k0 + cc]);
      cp16(&Bs[pb * 128 * BK + ci * 8], &WT[(size_t)(n0 + r) * DM + k0 + cc]);
    }
  };

  stage(0, 0);
  __syncthreads();

  for (int t = 0; t < DM / BK; ++t) {
    int pb = t & 1;
    if (t + 1 < DM / BK) stage(pb ^ 1, (t + 1) * BK);
    bf16x8 af[4], bfr[4];
    for (int mt = 0; mt < 4; ++mt)
      af[mt] = *(const bf16x8*)&As[pb * 128 * BK + (wm + mt * 16 + l15) * BK + qd * 8];
    for (int nt = 0; nt < 4; ++nt)
      bfr[nt] = *(const bf16x8*)&Bs[pb * 128 * BK + (wn + nt * 16 + l15) * BK + qd * 8];
    for (int mt = 0; mt < 4; ++mt)
      for (int nt = 0; nt < 4; ++nt)
        acc[mt][nt] = __builtin_amdgcn_mfma_f32_16x16x32_bf16(
            af[mt], bfr[nt], acc[mt][nt], 0, 0, 0);
    __syncthreads();
  }

  const float* bias = (which == 0) ? bq : (which == 1) ? bk : bv;

  if (which == 2) {
    // V: bias + transpose via LDS, store vt[d][s]
    for (int nt = 0; nt < 4; ++nt) {
      int cl = wn + nt * 16 + l15;               // local col (d)
      float bv_ = bias[(n0 & 1023) + cl];
      for (int mt = 0; mt < 4; ++mt)
        for (int r = 0; r < 4; ++r)
          Ts[cl * TST + wm + mt * 16 + qd * 4 + r] = (bf16)(acc[mt][nt][r] + bv_);
    }
    __syncthreads();
    int chunk = tid & 15, colb = tid >> 4;
    for (int p = 0; p < 8; ++p) {
      int cl = p * 16 + colb;
      bf16x8 vv = *(const bf16x8*)&Ts[cl * TST + chunk * 8];
      *(bf16x8*)&vt[(size_t)((n0 & 1023) + cl) * MROWS + m0 + chunk * 8] = vv;
    }
  } else {
    bf16* out = (which == 0) ? qb : kb;
    float sc = (which == 0) ? QSCALE : 1.0f;
    for (int nt = 0; nt < 4; ++nt) {
      int col = (n0 & 1023) + wn + nt * 16 + l15;
      float bv_ = bias[col];
      for (int mt = 0; mt < 4; ++mt)
        for (int r = 0; r < 4; ++r) {
          int row = m0 + wm + mt * 16 + qd * 4 + r;
          out[(size_t)row * DM + col] = (bf16)((acc[mt][nt][r] + bv_) * sc);
        }
    }
  }
}

// ---------------------------------------------------------------------------
// Out-proj GEMM: C[M,N] = A @ WT^T + bias, fp32 out.  64x128 tile.
// m0 <- blockIdx.x (128 tiles), n0 <- blockIdx.y (8 tiles): grid (128, 8).
// 4 waves of 32x64.
// ---------------------------------------------------------------------------
__global__ __launch_bounds__(256, 4) void gemm_out(
    const bf16* __restrict__ A, const bf16* __restrict__ WT,
    const float* __restrict__ bias, float* __restrict__ C) {
  __shared__ __align__(16) bf16 As[2][64 * BK];
  __shared__ __align__(16) bf16 Bs[2][128 * BK];
  int tid = threadIdx.x;
  int lane = tid & 63, w = tid >> 6;
  int wm = (w >> 1) * 32;
  int wn = (w & 1) * 64;
  int m0 = blockIdx.x * 64;
  int n0 = blockIdx.y * 128;
  int qd = lane >> 4;
  int l15 = lane & 15;

  floatx4 acc[2][4] = {};

  auto stage = [&](int pb, int k0) {
    {  // A: 256 chunks, 1/thread
      int ci = w * 64;
      int c = ci + lane;
      int r = c >> 2, cc = (c & 3) * 8;
      cp16(&As[pb][ci * 8], &A[(size_t)(m0 + r) * DM + k0 + cc]);
    }
    for (int i = 0; i < 2; ++i) {  // B: 512 chunks, 2/thread
      int ci = (w * 2 + i) * 64;
      int c = ci + lane;
      int r = c >> 2, cc = (c & 3) * 8;
      cp16(&Bs[pb][ci * 8], &WT[(size_t)(n0 + r) * DM + k0 + cc]);
    }
  };

  stage(0, 0);
  __syncthreads();

  for (int t = 0; t < DM / BK; ++t) {
    int pb = t & 1;
    if (t + 1 < DM / BK) stage(pb ^ 1, (t + 1) * BK);
    bf16x8 af[2], bfr[4];
    for (int mt = 0; mt < 2; ++mt)
      af[mt] = *(const bf16x8*)&As[pb][(wm + mt * 16 + l15) * BK + qd * 8];
    for (int nt = 0; nt < 4; ++nt)
      bfr[nt] = *(const bf16x8*)&Bs[pb][(wn + nt * 16 + l15) * BK + qd * 8];
    for (int mt = 0; mt < 2; ++mt)
      for (int nt = 0; nt < 4; ++nt)
        acc[mt][nt] = __builtin_amdgcn_mfma_f32_16x16x32_bf16(
            af[mt], bfr[nt], acc[mt][nt], 0, 0, 0);
    __syncthreads();
  }

  for (int nt = 0; nt < 4; ++nt) {
    int col = n0 + wn + nt * 16 + l15;
    float bv = bias[col];
    for (int mt = 0; mt < 2; ++mt)
      for (int r = 0; r < 4; ++r) {
        int row = m0 + wm + mt * 16 + qd * 4 + r;
        C[(size_t)row * DM + col] = acc[mt][nt][r] + bv;
      }
  }
}

// ---------------------------------------------------------------------------
// Flash attention, causal.  One block = one 128-row q-tile; grid (16,16,4)
// with qt = 15-bx (heavy blocks dispatch first).  3 blocks/CU (LDS 51 KB).
// 4 waves x 32 q-rows, K-tile 64 keys, XOR-swizzled unpadded K/V staging via
// global_load_lds, single-barrier double-buffer.  Q arrives pre-scaled by
// 0.125*log2e; V pre-transposed (vt[d][s]).  Shared max per 16-row group;
// l-sum via MFMA-ones; Ps wave-private (no barrier).
// ---------------------------------------------------------------------------
__global__ __launch_bounds__(256, 3) void attn_fwd(
    const bf16* __restrict__ Qg, const bf16* __restrict__ Kg,
    const bf16* __restrict__ Vt, bf16* __restrict__ O) {
  __shared__ __align__(16) bf16 Kbuf[2][64 * 64];
  __shared__ __align__(16) bf16 Vbuf[2][64 * 64];
  __shared__ __align__(16) bf16 Ps[4][32][72];

  int tid = threadIdx.x;
  int lane = tid & 63, w = tid >> 6;
  int qd = lane >> 4, l15 = lane & 15;
  int sw = l15 & 7;
  int qt = 15 - blockIdx.x, h = blockIdx.y, b = blockIdx.z;
  int base = b * SS;
  int hoff = h * DH;
  int q0 = qt * 128;
  int nkt = 2 * qt + 2;

  int gch = ((lane & 7) ^ (lane >> 3)) * 8;
  auto stage = [&](int pb, int kt) {
    int kbase = base + kt * 64;
    for (int i = 0; i < 2; ++i) {
      int ci = (w * 2 + i) * 64;
      int row = (ci + lane) >> 3;
      cp16(&Kbuf[pb][ci * 8], &Kg[(size_t)(kbase + row) * DM + hoff + gch]);
      cp16(&Vbuf[pb][ci * 8],
           &Vt[(size_t)(hoff + row) * MROWS + base + kt * 64 + gch]);
    }
  };

  bf16x8 onesf;
  for (int j = 0; j < 8; ++j) onesf[j] = (bf16)1.0f;

  stage(0, 0);

  bf16x8 qf[2][2];
  for (int mt = 0; mt < 2; ++mt) {
    int qrow = base + q0 + w * 32 + mt * 16 + l15;
    for (int ks = 0; ks < 2; ++ks)
      qf[mt][ks] = *(const bf16x8*)&Qg[(size_t)qrow * DM + hoff + ks * 32 + qd * 8];
  }

  float m_r[2] = {-3e38f, -3e38f};
  floatx4 lacc[2] = {};
  floatx4 oacc[2][4] = {};

  __syncthreads();  // drains tile-0 loads

  for (int kt = 0; kt < nkt; ++kt) {
    int pb = kt & 1;
    if (kt + 1 < nkt) stage(pb ^ 1, kt + 1);

    floatx4 s[2][4] = {};
    for (int ks = 0; ks < 2; ++ks)
      for (int nt = 0; nt < 4; ++nt) {
        bf16x8 kf = *(const bf16x8*)
            &Kbuf[pb][(nt * 16 + l15) * 64 + (((ks << 2) + qd) ^ sw) * 8];
        s[0][nt] = __builtin_amdgcn_mfma_f32_16x16x32_bf16(
            qf[0][ks], kf, s[0][nt], 0, 0, 0);
        s[1][nt] = __builtin_amdgcn_mfma_f32_16x16x32_bf16(
            qf[1][ks], kf, s[1][nt], 0, 0, 0);
      }

    if (kt >= 2 * qt) {
      for (int mt = 0; mt < 2; ++mt)
        for (int nt = 0; nt < 4; ++nt) {
          int col = kt * 64 + nt * 16 + l15;
          for (int r = 0; r < 4; ++r) {
            int row = q0 + w * 32 + mt * 16 + qd * 4 + r;
            if (col > row) s[mt][nt][r] = -3e38f;
          }
        }
    }

    for (int mt = 0; mt < 2; ++mt) {
      float t = s[mt][0][0];
      for (int nt = 0; nt < 4; ++nt)
        for (int r = 0; r < 4; ++r) t = fmaxf(t, s[mt][nt][r]);
      t = fmaxf(t, __shfl_xor(t, 1, 64));
      t = fmaxf(t, __shfl_xor(t, 2, 64));
      t = fmaxf(t, __shfl_xor(t, 4, 64));
      t = fmaxf(t, __shfl_xor(t, 8, 64));
      float mn = fmaxf(m_r[mt], t);
      float al = EXP2F(m_r[mt] - mn);
      m_r[mt] = mn;
      for (int dt = 0; dt < 4; ++dt)
        for (int r = 0; r < 4; ++r) oacc[mt][dt][r] *= al;
      for (int r = 0; r < 4; ++r) lacc[mt][r] *= al;
      for (int nt = 0; nt < 4; ++nt)
        for (int r = 0; r < 4; ++r) {
          float p = EXP2F(s[mt][nt][r] - mn);
          Ps[w][mt * 16 + qd * 4 + r][nt * 16 + l15] = (bf16)p;
        }
    }

    bf16x8 pf[2][2];
    for (int mt = 0; mt < 2; ++mt)
      for (int ks = 0; ks < 2; ++ks)
        pf[mt][ks] = *(const bf16x8*)&Ps[w][mt * 16 + l15][ks * 32 + qd * 8];

    for (int ks = 0; ks < 2; ++ks)
      for (int dt = 0; dt < 4; ++dt) {
        bf16x8 vf = *(const bf16x8*)
            &Vbuf[pb][(dt * 16 + l15) * 64 + (((ks << 2) + qd) ^ sw) * 8];
        oacc[0][dt] = __builtin_amdgcn_mfma_f32_16x16x32_bf16(
            pf[0][ks], vf, oacc[0][dt], 0, 0, 0);
        oacc[1][dt] = __builtin_amdgcn_mfma_f32_16x16x32_bf16(
            pf[1][ks], vf, oacc[1][dt], 0, 0, 0);
      }
    for (int mt = 0; mt < 2; ++mt)
      for (int ks = 0; ks < 2; ++ks)
        lacc[mt] = __builtin_amdgcn_mfma_f32_16x16x32_bf16(
            pf[mt][ks], onesf, lacc[mt], 0, 0, 0);

    __syncthreads();
  }

  for (int mt = 0; mt < 2; ++mt)
    for (int r = 0; r < 4; ++r) {
      float inv = 1.0f / lacc[mt][r];
      int row = base + q0 + w * 32 + mt * 16 + qd * 4 + r;
      for (int dt = 0; dt < 4; ++dt)
        O[(size_t)row * DM + hoff + dt * 16 + l15] = (bf16)(oacc[mt][dt][r] * inv);
    }
}

// ---------------------------------------------------------------------------
extern "C" void kernel_launch(void* const* d_in, const int* in_sizes, int n_in,
                              void* d_out, int out_size, void* d_ws, size_t ws_size,
                              hipStream_t stream) {
  const float* x  = (const float*)d_in[0];
  const float* Wq = (const float*)d_in[1];
  const float* bq = (const float*)d_in[2];
  const float* Wk = (const float*)d_in[3];
  const float* bk = (const float*)d_in[4];
  const float* Wv = (const float*)d_in[5];
  const float* bv = (const float*)d_in[6];
  const float* Wo = (const float*)d_in[7];
  const float* bo = (const float*)d_in[8];
  float* out = (float*)d_out;

  char* ws = (char*)d_ws;
  const size_t act = (size_t)MROWS * DM * sizeof(bf16);  // 16.8 MB
  bf16* xb    = (bf16*)(ws);
  bf16* qb    = (bf16*)(ws + act);
  bf16* kb    = (bf16*)(ws + 2 * act);
  bf16* vt    = (bf16*)(ws + 3 * act);   // [1024][8192]
  bf16* ab    = (bf16*)(ws + 4 * act);
  bf16* WqkvT = (bf16*)(ws + 5 * act);   // [3072][1024]
  bf16* WoT   = WqkvT + 3 * (size_t)DM * DM;

  cvt_x<<<MROWS * DM / (256 * 8), 256, 0, stream>>>(x, xb);
  wtransc<<<dim3(32, 32, 4), dim3(32, 32), 0, stream>>>(
      Wq, Wk, Wv, Wo,
      WqkvT, WqkvT + (size_t)DM * DM, WqkvT + 2 * (size_t)DM * DM, WoT);

  gemm_qkv<<<dim3(24, 64), 256, 0, stream>>>(
      xb, WqkvT, bq, bk, bv, qb, kb, vt);

  attn_fwd<<<dim3(16, NH, BB), 256, 0, stream>>>(qb, kb, vt, ab);

  gemm_out<<<dim3(128, 8), 256, 0, stream>>>(ab, WoT, bo, out);
}

// Round 7
// 272.535 us; speedup vs baseline: 1.1638x; 1.1638x over previous
//
#include <hip/hip_runtime.h>
#include <math.h>

#define DM 1024
#define NH 16
#define DH 64
#define BB 4
#define SS 2048
#define MROWS (BB*SS)

typedef __bf16 bf16;
typedef __bf16 bf16x8 __attribute__((ext_vector_type(8)));
typedef float floatx4 __attribute__((ext_vector_type(4)));

#if __has_builtin(__builtin_amdgcn_exp2f)
#define EXP2F __builtin_amdgcn_exp2f
#else
#define EXP2F exp2f
#endif

#define QSCALE (0.125f * 1.44269504088896f)  // Dh^-0.5 * log2(e)

// async 16B global->LDS; lds dest = wave-uniform base + lane*16 (HW rule)
__device__ __forceinline__ void cp16(void* lds, const void* g) {
  __builtin_amdgcn_global_load_lds(
      (__attribute__((address_space(1))) void*)(void*)g,
      (__attribute__((address_space(3))) void*)lds,
      16, 0, 0);
}

// ---------------------------------------------------------------------------
// x: fp32 -> bf16
// ---------------------------------------------------------------------------
__global__ __launch_bounds__(256) void cvt_x(
    const float* __restrict__ X, bf16* __restrict__ Y) {
  int i = (blockIdx.x * 256 + threadIdx.x) * 8;
  float4 a = *(const float4*)&X[i];
  float4 b = *(const float4*)&X[i + 4];
  bf16x8 o;
  o[0] = (bf16)a.x; o[1] = (bf16)a.y; o[2] = (bf16)a.z; o[3] = (bf16)a.w;
  o[4] = (bf16)b.x; o[5] = (bf16)b.y; o[6] = (bf16)b.z; o[7] = (bf16)b.w;
  *(bf16x8*)&Y[i] = o;
}

// ---------------------------------------------------------------------------
// Weight convert+transpose: T[n][k] = (bf16)W[k][n].
// T0..T2 land contiguously (the fused QKV weight [3072][1024]); T3 = WoT.
// ---------------------------------------------------------------------------
__global__ __launch_bounds__(1024) void wtransc(
    const float* __restrict__ W0, const float* __restrict__ W1,
    const float* __restrict__ W2, const float* __restrict__ W3,
    bf16* __restrict__ T0, bf16* __restrict__ T1,
    bf16* __restrict__ T2, bf16* __restrict__ T3) {
  __shared__ float tile[32][33];
  const float* W; bf16* T;
  int z = blockIdx.z;
  if (z == 0)      { W = W0; T = T0; }
  else if (z == 1) { W = W1; T = T1; }
  else if (z == 2) { W = W2; T = T2; }
  else             { W = W3; T = T3; }
  int tx = threadIdx.x, ty = threadIdx.y;
  tile[ty][tx] = W[(blockIdx.y * 32 + ty) * DM + blockIdx.x * 32 + tx];
  __syncthreads();
  T[(blockIdx.x * 32 + ty) * DM + blockIdx.y * 32 + tx] = (bf16)tile[tx][ty];
}

// ---------------------------------------------------------------------------
// Fused QKV GEMM: [8192,1024] @ WqkvT[3072,1024]^T + bias.  128x128 tile,
// grid (24,64), 4 waves of 64x64, BK=32, global_load_lds double-buffer with
// single barrier per k-step.  Epilogue by output stream:
//   Q: (acc+b)*QSCALE -> qb          K: acc+b -> kb
//   V: acc+b -> LDS tile -> TRANSPOSED store into vt[d][s]
// ---------------------------------------------------------------------------
#define BK 32
#define TST 136  // V-transpose LDS tile stride (272 B = 17*16: b128-aligned)

__global__ __launch_bounds__(256, 3) void gemm_qkv(
    const bf16* __restrict__ A, const bf16* __restrict__ WT,
    const float* __restrict__ bq, const float* __restrict__ bk,
    const float* __restrict__ bv,
    bf16* __restrict__ qb, bf16* __restrict__ kb, bf16* __restrict__ vt) {
  __shared__ __align__(16) char smem[2 * 128 * BK * 2 * 2 > 128 * TST * 2
                                         ? 2 * 128 * BK * 2 * 2
                                         : 128 * TST * 2];
  bf16* As = (bf16*)smem;                    // [2][128*BK]
  bf16* Bs = (bf16*)smem + 2 * 128 * BK;     // [2][128*BK]
  bf16* Ts = (bf16*)smem;                    // [128][TST] (aliases, post-loop)

  int tid = threadIdx.x;
  int lane = tid & 63, w = tid >> 6;
  int wm = (w >> 1) * 64;
  int wn = (w & 1) * 64;
  int m0 = blockIdx.y * 128;
  int n0 = blockIdx.x * 128;      // global over 3072
  int which = n0 >> 10;           // 0=Q 1=K 2=V
  int qd = lane >> 4;
  int l15 = lane & 15;

  floatx4 acc[4][4] = {};

  auto stage = [&](int pb, int k0) {
    for (int i = 0; i < 2; ++i) {
      int ci = (w * 2 + i) * 64;
      int c = ci + lane;
      int r = c >> 2, cc = (c & 3) * 8;
      cp16(&As[pb * 128 * BK + ci * 8], &A[(size_t)(m0 + r) * DM + k0 + cc]);
      cp16(&Bs[pb * 128 * BK + ci * 8], &WT[(size_t)(n0 + r) * DM + k0 + cc]);
    }
  };

  stage(0, 0);
  __syncthreads();

  for (int t = 0; t < DM / BK; ++t) {
    int pb = t & 1;
    if (t + 1 < DM / BK) stage(pb ^ 1, (t + 1) * BK);
    bf16x8 af[4], bfr[4];
    for (int mt = 0; mt < 4; ++mt)
      af[mt] = *(const bf16x8*)&As[pb * 128 * BK + (wm + mt * 16 + l15) * BK + qd * 8];
    for (int nt = 0; nt < 4; ++nt)
      bfr[nt] = *(const bf16x8*)&Bs[pb * 128 * BK + (wn + nt * 16 + l15) * BK + qd * 8];
    for (int mt = 0; mt < 4; ++mt)
      for (int nt = 0; nt < 4; ++nt)
        acc[mt][nt] = __builtin_amdgcn_mfma_f32_16x16x32_bf16(
            af[mt], bfr[nt], acc[mt][nt], 0, 0, 0);
    __syncthreads();
  }

  const float* bias = (which == 0) ? bq : (which == 1) ? bk : bv;

  if (which == 2) {
    // V: bias + transpose via LDS, store vt[d][s]
    for (int nt = 0; nt < 4; ++nt) {
      int cl = wn + nt * 16 + l15;               // local col (d)
      float bv_ = bias[(n0 & 1023) + cl];
      for (int mt = 0; mt < 4; ++mt)
        for (int r = 0; r < 4; ++r)
          Ts[cl * TST + wm + mt * 16 + qd * 4 + r] = (bf16)(acc[mt][nt][r] + bv_);
    }
    __syncthreads();
    int chunk = tid & 15, colb = tid >> 4;
    for (int p = 0; p < 8; ++p) {
      int cl = p * 16 + colb;
      bf16x8 vv = *(const bf16x8*)&Ts[cl * TST + chunk * 8];
      *(bf16x8*)&vt[(size_t)((n0 & 1023) + cl) * MROWS + m0 + chunk * 8] = vv;
    }
  } else {
    bf16* out = (which == 0) ? qb : kb;
    float sc = (which == 0) ? QSCALE : 1.0f;
    for (int nt = 0; nt < 4; ++nt) {
      int col = (n0 & 1023) + wn + nt * 16 + l15;
      float bv_ = bias[col];
      for (int mt = 0; mt < 4; ++mt)
        for (int r = 0; r < 4; ++r) {
          int row = m0 + wm + mt * 16 + qd * 4 + r;
          out[(size_t)row * DM + col] = (bf16)((acc[mt][nt][r] + bv_) * sc);
        }
    }
  }
}

// ---------------------------------------------------------------------------
// Out-proj GEMM: C[M,N] = A @ WT^T + bias, fp32 out.  64x128 tile,
// grid (128, 8).  4 waves of 32x64.
// ---------------------------------------------------------------------------
__global__ __launch_bounds__(256, 4) void gemm_out(
    const bf16* __restrict__ A, const bf16* __restrict__ WT,
    const float* __restrict__ bias, float* __restrict__ C) {
  __shared__ __align__(16) bf16 As[2][64 * BK];
  __shared__ __align__(16) bf16 Bs[2][128 * BK];
  int tid = threadIdx.x;
  int lane = tid & 63, w = tid >> 6;
  int wm = (w >> 1) * 32;
  int wn = (w & 1) * 64;
  int m0 = blockIdx.x * 64;
  int n0 = blockIdx.y * 128;
  int qd = lane >> 4;
  int l15 = lane & 15;

  floatx4 acc[2][4] = {};

  auto stage = [&](int pb, int k0) {
    {  // A: 256 chunks, 1/thread
      int ci = w * 64;
      int c = ci + lane;
      int r = c >> 2, cc = (c & 3) * 8;
      cp16(&As[pb][ci * 8], &A[(size_t)(m0 + r) * DM + k0 + cc]);
    }
    for (int i = 0; i < 2; ++i) {  // B: 512 chunks, 2/thread
      int ci = (w * 2 + i) * 64;
      int c = ci + lane;
      int r = c >> 2, cc = (c & 3) * 8;
      cp16(&Bs[pb][ci * 8], &WT[(size_t)(n0 + r) * DM + k0 + cc]);
    }
  };

  stage(0, 0);
  __syncthreads();

  for (int t = 0; t < DM / BK; ++t) {
    int pb = t & 1;
    if (t + 1 < DM / BK) stage(pb ^ 1, (t + 1) * BK);
    bf16x8 af[2], bfr[4];
    for (int mt = 0; mt < 2; ++mt)
      af[mt] = *(const bf16x8*)&As[pb][(wm + mt * 16 + l15) * BK + qd * 8];
    for (int nt = 0; nt < 4; ++nt)
      bfr[nt] = *(const bf16x8*)&Bs[pb][(wn + nt * 16 + l15) * BK + qd * 8];
    for (int mt = 0; mt < 2; ++mt)
      for (int nt = 0; nt < 4; ++nt)
        acc[mt][nt] = __builtin_amdgcn_mfma_f32_16x16x32_bf16(
            af[mt], bfr[nt], acc[mt][nt], 0, 0, 0);
    __syncthreads();
  }

  for (int nt = 0; nt < 4; ++nt) {
    int col = n0 + wn + nt * 16 + l15;
    float bv = bias[col];
    for (int mt = 0; mt < 2; ++mt)
      for (int r = 0; r < 4; ++r) {
        int row = m0 + wm + mt * 16 + qd * 4 + r;
        C[(size_t)row * DM + col] = acc[mt][nt][r] + bv;
      }
  }
}

// ---------------------------------------------------------------------------
// Flash attention, causal.  PAIRED-UNIFORM grid: one block = two 128-row
// q-tiles (qt = pair and 15-pair) -> every block runs exactly 34 k-tiles;
// grid (8,16,4) = 512 blocks = exactly 2/CU, zero variance, zero tail
// (un-paired variant measured 131 vs 93 us - tail-dominated).  4 waves x
// 32 q-rows; K-tile 64 keys; XOR-swizzled unpadded K/V staging via
// global_load_lds, single-barrier double-buffer.  Q arrives pre-scaled by
// 0.125*log2e (fused into gemm_qkv).  V pre-transposed (vt[d][s]).
// Shared max per 16-row group; l-sum via MFMA-ones; Ps wave-private.
// ---------------------------------------------------------------------------
__global__ __launch_bounds__(256, 2) void attn_fwd(
    const bf16* __restrict__ Qg, const bf16* __restrict__ Kg,
    const bf16* __restrict__ Vt, bf16* __restrict__ O) {
  __shared__ __align__(16) bf16 Kbuf[2][64 * 64];
  __shared__ __align__(16) bf16 Vbuf[2][64 * 64];
  __shared__ __align__(16) bf16 Ps[4][32][72];

  int tid = threadIdx.x;
  int lane = tid & 63, w = tid >> 6;
  int qd = lane >> 4, l15 = lane & 15;
  int sw = l15 & 7;
  int pair = blockIdx.x, h = blockIdx.y, b = blockIdx.z;
  int base = b * SS;
  int hoff = h * DH;

  int gch = ((lane & 7) ^ (lane >> 3)) * 8;
  auto stage = [&](int pb, int kt) {
    int kbase = base + kt * 64;
    for (int i = 0; i < 2; ++i) {
      int ci = (w * 2 + i) * 64;
      int row = (ci + lane) >> 3;
      cp16(&Kbuf[pb][ci * 8], &Kg[(size_t)(kbase + row) * DM + hoff + gch]);
      cp16(&Vbuf[pb][ci * 8],
           &Vt[(size_t)(hoff + row) * MROWS + base + kt * 64 + gch]);
    }
  };

  bf16x8 onesf;
  for (int j = 0; j < 8; ++j) onesf[j] = (bf16)1.0f;

  for (int ph = 0; ph < 2; ++ph) {
    int qt = ph ? (15 - pair) : pair;
    int q0 = qt * 128;
    int nkt = 2 * qt + 2;

    stage(0, 0);  // safe: previous phase's last kt-barrier covers buffer 0

    bf16x8 qf[2][2];
    for (int mt = 0; mt < 2; ++mt) {
      int qrow = base + q0 + w * 32 + mt * 16 + l15;
      for (int ks = 0; ks < 2; ++ks)
        qf[mt][ks] = *(const bf16x8*)&Qg[(size_t)qrow * DM + hoff + ks * 32 + qd * 8];
    }

    float m_r[2] = {-3e38f, -3e38f};
    floatx4 lacc[2] = {};
    floatx4 oacc[2][4] = {};

    __syncthreads();  // drains tile-0 loads (vmcnt(0) before s_barrier)

    for (int kt = 0; kt < nkt; ++kt) {
      int pb = kt & 1;
      if (kt + 1 < nkt) stage(pb ^ 1, kt + 1);

      floatx4 s[2][4] = {};
      for (int ks = 0; ks < 2; ++ks)
        for (int nt = 0; nt < 4; ++nt) {
          bf16x8 kf = *(const bf16x8*)
              &Kbuf[pb][(nt * 16 + l15) * 64 + (((ks << 2) + qd) ^ sw) * 8];
          s[0][nt] = __builtin_amdgcn_mfma_f32_16x16x32_bf16(
              qf[0][ks], kf, s[0][nt], 0, 0, 0);
          s[1][nt] = __builtin_amdgcn_mfma_f32_16x16x32_bf16(
              qf[1][ks], kf, s[1][nt], 0, 0, 0);
        }

      if (kt >= 2 * qt) {  // diagonal tiles: causal mask
        for (int mt = 0; mt < 2; ++mt)
          for (int nt = 0; nt < 4; ++nt) {
            int col = kt * 64 + nt * 16 + l15;
            for (int r = 0; r < 4; ++r) {
              int row = q0 + w * 32 + mt * 16 + qd * 4 + r;
              if (col > row) s[mt][nt][r] = -3e38f;
            }
          }
      }

      for (int mt = 0; mt < 2; ++mt) {
        float t = s[mt][0][0];
        for (int nt = 0; nt < 4; ++nt)
          for (int r = 0; r < 4; ++r) t = fmaxf(t, s[mt][nt][r]);
        t = fmaxf(t, __shfl_xor(t, 1, 64));
        t = fmaxf(t, __shfl_xor(t, 2, 64));
        t = fmaxf(t, __shfl_xor(t, 4, 64));
        t = fmaxf(t, __shfl_xor(t, 8, 64));
        float mn = fmaxf(m_r[mt], t);
        float al = EXP2F(m_r[mt] - mn);
        m_r[mt] = mn;
        for (int dt = 0; dt < 4; ++dt)
          for (int r = 0; r < 4; ++r) oacc[mt][dt][r] *= al;
        for (int r = 0; r < 4; ++r) lacc[mt][r] *= al;
        for (int nt = 0; nt < 4; ++nt)
          for (int r = 0; r < 4; ++r) {
            float p = EXP2F(s[mt][nt][r] - mn);
            Ps[w][mt * 16 + qd * 4 + r][nt * 16 + l15] = (bf16)p;
          }
      }

      bf16x8 pf[2][2];
      for (int mt = 0; mt < 2; ++mt)
        for (int ks = 0; ks < 2; ++ks)
          pf[mt][ks] = *(const bf16x8*)&Ps[w][mt * 16 + l15][ks * 32 + qd * 8];

      for (int ks = 0; ks < 2; ++ks)
        for (int dt = 0; dt < 4; ++dt) {
          bf16x8 vf = *(const bf16x8*)
              &Vbuf[pb][(dt * 16 + l15) * 64 + (((ks << 2) + qd) ^ sw) * 8];
          oacc[0][dt] = __builtin_amdgcn_mfma_f32_16x16x32_bf16(
              pf[0][ks], vf, oacc[0][dt], 0, 0, 0);
          oacc[1][dt] = __builtin_amdgcn_mfma_f32_16x16x32_bf16(
              pf[1][ks], vf, oacc[1][dt], 0, 0, 0);
        }
      for (int mt = 0; mt < 2; ++mt)
        for (int ks = 0; ks < 2; ++ks)
          lacc[mt] = __builtin_amdgcn_mfma_f32_16x16x32_bf16(
              pf[mt][ks], onesf, lacc[mt], 0, 0, 0);

      __syncthreads();  // single barrier/tile: drains async loads post-compute
    }

    for (int mt = 0; mt < 2; ++mt)
      for (int r = 0; r < 4; ++r) {
        float inv = 1.0f / lacc[mt][r];
        int row = base + q0 + w * 32 + mt * 16 + qd * 4 + r;
        for (int dt = 0; dt < 4; ++dt)
          O[(size_t)row * DM + hoff + dt * 16 + l15] = (bf16)(oacc[mt][dt][r] * inv);
      }
  }
}

// ---------------------------------------------------------------------------
extern "C" void kernel_launch(void* const* d_in, const int* in_sizes, int n_in,
                              void* d_out, int out_size, void* d_ws, size_t ws_size,
                              hipStream_t stream) {
  const float* x  = (const float*)d_in[0];
  const float* Wq = (const float*)d_in[1];
  const float* bq = (const float*)d_in[2];
  const float* Wk = (const float*)d_in[3];
  const float* bk = (const float*)d_in[4];
  const float* Wv = (const float*)d_in[5];
  const float* bv = (const float*)d_in[6];
  const float* Wo = (const float*)d_in[7];
  const float* bo = (const float*)d_in[8];
  float* out = (float*)d_out;

  char* ws = (char*)d_ws;
  const size_t act = (size_t)MROWS * DM * sizeof(bf16);  // 16.8 MB
  bf16* xb    = (bf16*)(ws);
  bf16* qb    = (bf16*)(ws + act);
  bf16* kb    = (bf16*)(ws + 2 * act);
  bf16* vt    = (bf16*)(ws + 3 * act);   // [1024][8192]
  bf16* ab    = (bf16*)(ws + 4 * act);
  bf16* WqkvT = (bf16*)(ws + 5 * act);   // [3072][1024]
  bf16* WoT   = WqkvT + 3 * (size_t)DM * DM;

  cvt_x<<<MROWS * DM / (256 * 8), 256, 0, stream>>>(x, xb);
  wtransc<<<dim3(32, 32, 4), dim3(32, 32), 0, stream>>>(
      Wq, Wk, Wv, Wo,
      WqkvT, WqkvT + (size_t)DM * DM, WqkvT + 2 * (size_t)DM * DM, WoT);

  gemm_qkv<<<dim3(24, 64), 256, 0, stream>>>(
      xb, WqkvT, bq, bk, bv, qb, kb, vt);

  attn_fwd<<<dim3(8, NH, BB), 256, 0, stream>>>(qb, kb, vt, ab);

  gemm_out<<<dim3(128, 8), 256, 0, stream>>>(ab, WoT, bo, out);
}